// Round 1
// baseline (467.106 us; speedup 1.0000x reference)
//
#include <hip/hip_runtime.h>

// GCN forward on MI355X (gfx950), fp32.
//   support1 = X @ W1                  [50000,128]x[128,64]
//   agg1     = b1 + A·support1         (edge scatter, atomics)
//   h        = relu(agg1)              (fused into GEMM2 load)
//   support2 = h @ W2                  [50000,64]x[64,64]
//   out      = b2 + A·support2         (edge scatter, atomics)

#define N_NODES 50000
#define N_EDGES 800000
#define IN_DIM  128
#define HID_DIM 64
#define OUT_DIM 64

// ---------------- GEMM1: [N,128] @ [128,64] -> [N,64] ----------------
// Block = 256 threads = 4 waves; each wave owns one row, lane = output col.
// W1 (32 KB) staged in LDS. LDS read Wl[k*64+col]: 64 lanes stride 4B over
// 32 banks = 2-way aliasing = free. x row read is wave-uniform (HW broadcast).
__global__ __launch_bounds__(256) void k_gemm_k128(
    const float* __restrict__ X, const float* __restrict__ W,
    float* __restrict__ out)
{
    __shared__ float Wl[IN_DIM * HID_DIM];
    int t = threadIdx.x;
    #pragma unroll
    for (int i = 0; i < (IN_DIM * HID_DIM) / 256; ++i)
        Wl[t + i * 256] = W[t + i * 256];
    __syncthreads();

    int row = blockIdx.x * 4 + (t >> 6);   // grid sized exactly: 50000/4
    int col = t & 63;
    const float* xr = X + (size_t)row * IN_DIM;
    float acc = 0.f;
    #pragma unroll 8
    for (int k = 0; k < IN_DIM; ++k)
        acc = fmaf(xr[k], Wl[k * HID_DIM + col], acc);
    out[(size_t)row * HID_DIM + col] = acc;
}

// ---------------- GEMM2: [N,64] @ [64,64] -> [N,64], relu on load ----
template <bool RELU_IN>
__global__ __launch_bounds__(256) void k_gemm_k64(
    const float* __restrict__ X, const float* __restrict__ W,
    float* __restrict__ out)
{
    __shared__ float Wl[HID_DIM * OUT_DIM];
    int t = threadIdx.x;
    #pragma unroll
    for (int i = 0; i < (HID_DIM * OUT_DIM) / 256; ++i)
        Wl[t + i * 256] = W[t + i * 256];
    __syncthreads();

    int row = blockIdx.x * 4 + (t >> 6);
    int col = t & 63;
    const float* xr = X + (size_t)row * HID_DIM;
    float acc = 0.f;
    #pragma unroll 8
    for (int k = 0; k < HID_DIM; ++k) {
        float xv = xr[k];
        if (RELU_IN) xv = fmaxf(xv, 0.f);
        acc = fmaf(xv, Wl[k * OUT_DIM + col], acc);
    }
    out[(size_t)row * OUT_DIM + col] = acc;
}

// ---------------- bias broadcast init: out[i*64+j] = b[j] ------------
__global__ __launch_bounds__(256) void k_bias_init(
    float* __restrict__ out, const float* __restrict__ b)
{
    int i = blockIdx.x * 256 + threadIdx.x;   // grid covers N_NODES*64 exactly
    out[i] = b[i & 63];
}

// ---------------- edge scatter: out[row] += val * dense[col] ---------
// One wave per edge; lane = feature dim. row/col/val loads are wave-uniform,
// dense row read is a coalesced 256B burst, atomics are a coalesced 256B
// burst to a random row.
__global__ __launch_bounds__(256) void k_scatter(
    const int* __restrict__ erow, const int* __restrict__ ecol,
    const float* __restrict__ eval_, const float* __restrict__ dense,
    float* __restrict__ out)
{
    long long tid = (long long)blockIdx.x * 256 + threadIdx.x;
    int e = (int)(tid >> 6);
    int d = (int)(tid & 63);
    float v = eval_[e];
    int c = ecol[e];
    int r = erow[e];
    atomicAdd(&out[(size_t)r * 64 + d], v * dense[(size_t)c * 64 + d]);
}

extern "C" void kernel_launch(void* const* d_in, const int* in_sizes, int n_in,
                              void* d_out, int out_size, void* d_ws, size_t ws_size,
                              hipStream_t stream)
{
    const float* x     = (const float*)d_in[0];
    const int*   erow  = (const int*)d_in[1];
    const int*   ecol  = (const int*)d_in[2];
    const float* eval_ = (const float*)d_in[3];
    const float* W1    = (const float*)d_in[4];
    const float* b1    = (const float*)d_in[5];
    const float* W2    = (const float*)d_in[6];
    const float* b2    = (const float*)d_in[7];
    float* out = (float*)d_out;

    // ws: two [50000,64] fp32 buffers (12.8 MB each). support buffer is
    // reused for layer 2 (support1 dead after scatter1).
    float* support = (float*)d_ws;                                  // ws0
    float* agg1    = support + (size_t)N_NODES * HID_DIM;           // ws1

    const int gemm_grid = N_NODES / 4;                 // 12500, exact
    const int vec_grid  = (N_NODES * HID_DIM) / 256;   // 12500, exact
    const int sc_grid   = (int)(((long long)N_EDGES * 64) / 256); // 200000

    // layer 1
    k_gemm_k128<<<gemm_grid, 256, 0, stream>>>(x, W1, support);
    k_bias_init<<<vec_grid, 256, 0, stream>>>(agg1, b1);
    k_scatter<<<sc_grid, 256, 0, stream>>>(erow, ecol, eval_, support, agg1);
    // layer 2 (relu fused into GEMM2's input load)
    k_gemm_k64<true><<<gemm_grid, 256, 0, stream>>>(agg1, W2, support);
    k_bias_init<<<vec_grid, 256, 0, stream>>>(out, b2);
    k_scatter<<<sc_grid, 256, 0, stream>>>(erow, ecol, eval_, support, out);
}

// Round 2
// 463.297 us; speedup vs baseline: 1.0082x; 1.0082x over previous
//
#include <hip/hip_runtime.h>

// GCN forward on MI355X (gfx950), fp32.
// R2: atomic scatter -> CSR build (hist/scan/reorder, once per launch,
// shared by both layers) + register-accumulating gather with fused bias.

#define N_NODES 50000
#define N_EDGES 800000
#define IN_DIM  128
#define HID_DIM 64
#define OUT_DIM 64

// ---------------- CSR build ----------------
__global__ __launch_bounds__(256) void k_zero(int* __restrict__ p, int n) {
    int i = blockIdx.x * 256 + threadIdx.x;
    if (i < n) p[i] = 0;
}

__global__ __launch_bounds__(256) void k_hist(const int* __restrict__ erow,
                                              int* __restrict__ counts) {
    int e = blockIdx.x * 256 + threadIdx.x;
    if (e < N_EDGES) atomicAdd(&counts[erow[e]], 1);
}

// Single-block scan: 512 threads x 98 sequential elements each.
#define SCAN_BLOCK 512
#define SCAN_SEQ   ((N_NODES + SCAN_BLOCK - 1) / SCAN_BLOCK)   // 98
__global__ __launch_bounds__(SCAN_BLOCK) void k_scan(
    const int* __restrict__ counts, int* __restrict__ offs,
    int* __restrict__ cursor)
{
    __shared__ int sm[SCAN_BLOCK];
    int t = threadIdx.x;
    int lo = t * SCAN_SEQ, hi = min(lo + SCAN_SEQ, N_NODES);
    int s = 0;
    for (int i = lo; i < hi; ++i) s += counts[i];
    sm[t] = s;
    __syncthreads();
    // inclusive scan across 512 thread-sums (Hillis-Steele)
    for (int off = 1; off < SCAN_BLOCK; off <<= 1) {
        int add = (t >= off) ? sm[t - off] : 0;
        __syncthreads();
        sm[t] += add;
        __syncthreads();
    }
    int run = sm[t] - s;   // exclusive prefix of this thread's range
    for (int i = lo; i < hi; ++i) {
        int c = counts[i];
        offs[i] = run;
        cursor[i] = run;
        run += c;
    }
    if (t == SCAN_BLOCK - 1) offs[N_NODES] = run;   // = N_EDGES
}

// Scatter edges into row-sorted (col, val_bits) pairs.
__global__ __launch_bounds__(256) void k_reorder(
    const int* __restrict__ erow, const int* __restrict__ ecol,
    const float* __restrict__ eval_, int* __restrict__ cursor,
    uint2* __restrict__ pairs)
{
    int e = blockIdx.x * 256 + threadIdx.x;
    if (e >= N_EDGES) return;
    int r = erow[e];
    int pos = atomicAdd(&cursor[r], 1);
    pairs[pos] = make_uint2((unsigned)ecol[e], __float_as_uint(eval_[e]));
}

// ---------------- gather SpMM: out[r] = bias + sum val*dense[col] ----
// One wave per row, lane = feature dim. Pair load is wave-uniform
// (HW broadcast); dense row read is a coalesced 256B burst; single
// coalesced store per row. No fp32 atomics anywhere.
__global__ __launch_bounds__(256) void k_gather(
    const int* __restrict__ offs, const uint2* __restrict__ pairs,
    const float* __restrict__ dense, const float* __restrict__ bias,
    float* __restrict__ out)
{
    int t = threadIdx.x;
    int r = blockIdx.x * 4 + (t >> 6);   // grid = 12500, exact
    int d = t & 63;
    int e0 = offs[r], e1 = offs[r + 1];
    float acc = bias[d];
    for (int e = e0; e < e1; ++e) {
        uint2 p = pairs[e];
        acc = fmaf(__uint_as_float(p.y), dense[(size_t)p.x * 64u + d], acc);
    }
    out[(size_t)r * 64 + d] = acc;
}

// ---------------- GEMM1: [N,128] @ [128,64] -> [N,64] ----------------
__global__ __launch_bounds__(256) void k_gemm_k128(
    const float* __restrict__ X, const float* __restrict__ W,
    float* __restrict__ out)
{
    __shared__ float Wl[IN_DIM * HID_DIM];
    int t = threadIdx.x;
    #pragma unroll
    for (int i = 0; i < (IN_DIM * HID_DIM) / 256; ++i)
        Wl[t + i * 256] = W[t + i * 256];
    __syncthreads();

    int row = blockIdx.x * 4 + (t >> 6);
    int col = t & 63;
    const float* xr = X + (size_t)row * IN_DIM;
    float acc = 0.f;
    #pragma unroll 8
    for (int k = 0; k < IN_DIM; ++k)
        acc = fmaf(xr[k], Wl[k * HID_DIM + col], acc);
    out[(size_t)row * HID_DIM + col] = acc;
}

// ---------------- GEMM2: [N,64] @ [64,64] -> [N,64], relu on load ----
template <bool RELU_IN>
__global__ __launch_bounds__(256) void k_gemm_k64(
    const float* __restrict__ X, const float* __restrict__ W,
    float* __restrict__ out)
{
    __shared__ float Wl[HID_DIM * OUT_DIM];
    int t = threadIdx.x;
    #pragma unroll
    for (int i = 0; i < (HID_DIM * OUT_DIM) / 256; ++i)
        Wl[t + i * 256] = W[t + i * 256];
    __syncthreads();

    int row = blockIdx.x * 4 + (t >> 6);
    int col = t & 63;
    const float* xr = X + (size_t)row * HID_DIM;
    float acc = 0.f;
    #pragma unroll 8
    for (int k = 0; k < HID_DIM; ++k) {
        float xv = xr[k];
        if (RELU_IN) xv = fmaxf(xv, 0.f);
        acc = fmaf(xv, Wl[k * OUT_DIM + col], acc);
    }
    out[(size_t)row * OUT_DIM + col] = acc;
}

extern "C" void kernel_launch(void* const* d_in, const int* in_sizes, int n_in,
                              void* d_out, int out_size, void* d_ws, size_t ws_size,
                              hipStream_t stream)
{
    const float* x     = (const float*)d_in[0];
    const int*   erow  = (const int*)d_in[1];
    const int*   ecol  = (const int*)d_in[2];
    const float* eval_ = (const float*)d_in[3];
    const float* W1    = (const float*)d_in[4];
    const float* b1    = (const float*)d_in[5];
    const float* W2    = (const float*)d_in[6];
    const float* b2    = (const float*)d_in[7];
    float* out = (float*)d_out;

    // ws layout (all 8B-aligned; ~32.6 MB total):
    //   pairs   [800000] uint2          6.40 MB
    //   support [50000*64] f32         12.80 MB
    //   agg1    [50000*64] f32         12.80 MB
    //   counts  [50000] i32             0.20 MB
    //   offs    [50001] i32             0.20 MB
    //   cursor  [50000] i32             0.20 MB
    uint2* pairs   = (uint2*)d_ws;
    float* support = (float*)(pairs + N_EDGES);
    float* agg1    = support + (size_t)N_NODES * HID_DIM;
    int*   counts  = (int*)(agg1 + (size_t)N_NODES * HID_DIM);
    int*   offs    = counts + N_NODES;
    int*   cursor  = offs + (N_NODES + 1);

    const int zero_grid = (N_NODES + 255) / 256;     // 196
    const int edge_grid = (N_EDGES + 255) / 256;     // 3125
    const int row_grid  = N_NODES / 4;               // 12500, exact

    // CSR build (shared by both layers)
    k_zero<<<zero_grid, 256, 0, stream>>>(counts, N_NODES);
    k_hist<<<edge_grid, 256, 0, stream>>>(erow, counts);
    k_scan<<<1, SCAN_BLOCK, 0, stream>>>(counts, offs, cursor);
    k_reorder<<<edge_grid, 256, 0, stream>>>(erow, ecol, eval_, cursor, pairs);

    // layer 1
    k_gemm_k128<<<row_grid, 256, 0, stream>>>(x, W1, support);
    k_gather<<<row_grid, 256, 0, stream>>>(offs, pairs, support, b1, agg1);
    // layer 2 (relu fused into GEMM2's input load)
    k_gemm_k64<true><<<row_grid, 256, 0, stream>>>(agg1, W2, support);
    k_gather<<<row_grid, 256, 0, stream>>>(offs, pairs, support, b2, out);
}

// Round 3
// 276.356 us; speedup vs baseline: 1.6902x; 1.6765x over previous
//
#include <hip/hip_runtime.h>

// GCN forward on MI355X (gfx950), fp32.
// R3: hierarchical CSR scan (the R2 single-block scan was a 117us serial
// bottleneck) + readfirstlane to force scalar loads on wave-uniform data.

#define N_NODES 50000
#define N_EDGES 800000
#define IN_DIM  128
#define HID_DIM 64
#define OUT_DIM 64

#define SCAN_B 256
#define N_SCAN_BLOCKS ((N_NODES + SCAN_B - 1) / SCAN_B)   // 196

// ---------------- CSR build ----------------
__global__ __launch_bounds__(256) void k_zero(int* __restrict__ p, int n) {
    int i = blockIdx.x * 256 + threadIdx.x;
    if (i < n) p[i] = 0;
}

__global__ __launch_bounds__(256) void k_hist(const int* __restrict__ erow,
                                              int* __restrict__ counts) {
    int e = blockIdx.x * 256 + threadIdx.x;
    if (e < N_EDGES) atomicAdd(&counts[erow[e]], 1);
}

// pass 1: per-block exclusive scan of counts; block total -> partials
__global__ __launch_bounds__(SCAN_B) void k_scan1(
    const int* __restrict__ counts, int* __restrict__ offs,
    int* __restrict__ partials)
{
    __shared__ int sm[SCAN_B];
    int t = threadIdx.x;
    int i = blockIdx.x * SCAN_B + t;
    int v = (i < N_NODES) ? counts[i] : 0;
    sm[t] = v;
    __syncthreads();
    #pragma unroll
    for (int off = 1; off < SCAN_B; off <<= 1) {
        int add = (t >= off) ? sm[t - off] : 0;
        __syncthreads();
        sm[t] += add;
        __syncthreads();
    }
    if (i < N_NODES) offs[i] = sm[t] - v;            // local exclusive
    if (t == SCAN_B - 1) partials[blockIdx.x] = sm[t];
}

// pass 2: exclusive scan of the 196 block totals (single tiny block)
__global__ __launch_bounds__(SCAN_B) void k_scan2(int* __restrict__ partials)
{
    __shared__ int sm[SCAN_B];
    int t = threadIdx.x;
    int v = (t < N_SCAN_BLOCKS) ? partials[t] : 0;
    sm[t] = v;
    __syncthreads();
    #pragma unroll
    for (int off = 1; off < SCAN_B; off <<= 1) {
        int add = (t >= off) ? sm[t - off] : 0;
        __syncthreads();
        sm[t] += add;
        __syncthreads();
    }
    if (t < N_SCAN_BLOCKS) partials[t] = sm[t] - v;  // exclusive
}

// pass 3: add block base; emit final offs + cursor copy
__global__ __launch_bounds__(SCAN_B) void k_scan3(
    int* __restrict__ offs, const int* __restrict__ partials,
    int* __restrict__ cursor)
{
    int t = threadIdx.x;
    int i = blockIdx.x * SCAN_B + t;
    int base = partials[blockIdx.x];
    if (i < N_NODES) {
        int o = offs[i] + base;
        offs[i] = o;
        cursor[i] = o;
    }
    if (i == 0) offs[N_NODES] = N_EDGES;
}

// Scatter edges into row-sorted (col, val_bits) pairs.
__global__ __launch_bounds__(256) void k_reorder(
    const int* __restrict__ erow, const int* __restrict__ ecol,
    const float* __restrict__ eval_, int* __restrict__ cursor,
    uint2* __restrict__ pairs)
{
    int e = blockIdx.x * 256 + threadIdx.x;
    if (e >= N_EDGES) return;
    int r = erow[e];
    int pos = atomicAdd(&cursor[r], 1);
    pairs[pos] = make_uint2((unsigned)ecol[e], __float_as_uint(eval_[e]));
}

// ---------------- gather SpMM: out[r] = bias + sum val*dense[col] ----
// One wave per row, lane = feature dim. r forced to SGPR so offs/pairs
// loads become scalar (s_load) instead of 64-lane broadcast loads.
__global__ __launch_bounds__(256) void k_gather(
    const int* __restrict__ offs, const uint2* __restrict__ pairs,
    const float* __restrict__ dense, const float* __restrict__ bias,
    float* __restrict__ out)
{
    int t = threadIdx.x;
    int r = __builtin_amdgcn_readfirstlane(blockIdx.x * 4 + (t >> 6));
    int d = t & 63;
    int e0 = offs[r], e1 = offs[r + 1];
    float acc = bias[d];
    for (int e = e0; e < e1; ++e) {
        uint2 p = pairs[e];
        acc = fmaf(__uint_as_float(p.y), dense[(size_t)p.x * 64u + d], acc);
    }
    out[(size_t)r * 64 + d] = acc;
}

// ---------------- GEMM1: [N,128] @ [128,64] -> [N,64] ----------------
__global__ __launch_bounds__(256) void k_gemm_k128(
    const float* __restrict__ X, const float* __restrict__ W,
    float* __restrict__ out)
{
    __shared__ float Wl[IN_DIM * HID_DIM];
    int t = threadIdx.x;
    #pragma unroll
    for (int i = 0; i < (IN_DIM * HID_DIM) / 256; ++i)
        Wl[t + i * 256] = W[t + i * 256];
    __syncthreads();

    int row = __builtin_amdgcn_readfirstlane(blockIdx.x * 4 + (t >> 6));
    int col = t & 63;
    const float* xr = X + (size_t)row * IN_DIM;   // scalar pointer -> s_load
    float acc = 0.f;
    #pragma unroll 8
    for (int k = 0; k < IN_DIM; ++k)
        acc = fmaf(xr[k], Wl[k * HID_DIM + col], acc);
    out[(size_t)row * HID_DIM + col] = acc;
}

// ---------------- GEMM2: [N,64] @ [64,64] -> [N,64], relu on load ----
template <bool RELU_IN>
__global__ __launch_bounds__(256) void k_gemm_k64(
    const float* __restrict__ X, const float* __restrict__ W,
    float* __restrict__ out)
{
    __shared__ float Wl[HID_DIM * OUT_DIM];
    int t = threadIdx.x;
    #pragma unroll
    for (int i = 0; i < (HID_DIM * OUT_DIM) / 256; ++i)
        Wl[t + i * 256] = W[t + i * 256];
    __syncthreads();

    int row = __builtin_amdgcn_readfirstlane(blockIdx.x * 4 + (t >> 6));
    int col = t & 63;
    const float* xr = X + (size_t)row * HID_DIM;
    float acc = 0.f;
    #pragma unroll 8
    for (int k = 0; k < HID_DIM; ++k) {
        float xv = xr[k];
        if (RELU_IN) xv = fmaxf(xv, 0.f);
        acc = fmaf(xv, Wl[k * OUT_DIM + col], acc);
    }
    out[(size_t)row * OUT_DIM + col] = acc;
}

extern "C" void kernel_launch(void* const* d_in, const int* in_sizes, int n_in,
                              void* d_out, int out_size, void* d_ws, size_t ws_size,
                              hipStream_t stream)
{
    const float* x     = (const float*)d_in[0];
    const int*   erow  = (const int*)d_in[1];
    const int*   ecol  = (const int*)d_in[2];
    const float* eval_ = (const float*)d_in[3];
    const float* W1    = (const float*)d_in[4];
    const float* b1    = (const float*)d_in[5];
    const float* W2    = (const float*)d_in[6];
    const float* b2    = (const float*)d_in[7];
    float* out = (float*)d_out;

    // ws layout (~32.6 MB):
    uint2* pairs    = (uint2*)d_ws;                                  // 6.4 MB
    float* support  = (float*)(pairs + N_EDGES);                     // 12.8 MB
    float* agg1     = support + (size_t)N_NODES * HID_DIM;           // 12.8 MB
    int*   counts   = (int*)(agg1 + (size_t)N_NODES * HID_DIM);      // 0.2 MB
    int*   offs     = counts + N_NODES;                              // 0.2 MB
    int*   cursor   = offs + (N_NODES + 1);                          // 0.2 MB
    int*   partials = cursor + N_NODES;                              // 784 B

    const int zero_grid = (N_NODES + 255) / 256;     // 196
    const int edge_grid = (N_EDGES + 255) / 256;     // 3125
    const int row_grid  = N_NODES / 4;               // 12500, exact

    // CSR build (shared by both layers)
    k_zero<<<zero_grid, 256, 0, stream>>>(counts, N_NODES);
    k_hist<<<edge_grid, 256, 0, stream>>>(erow, counts);
    k_scan1<<<N_SCAN_BLOCKS, SCAN_B, 0, stream>>>(counts, offs, partials);
    k_scan2<<<1, SCAN_B, 0, stream>>>(partials);
    k_scan3<<<N_SCAN_BLOCKS, SCAN_B, 0, stream>>>(offs, partials, cursor);
    k_reorder<<<edge_grid, 256, 0, stream>>>(erow, ecol, eval_, cursor, pairs);

    // layer 1
    k_gemm_k128<<<row_grid, 256, 0, stream>>>(x, W1, support);
    k_gather<<<row_grid, 256, 0, stream>>>(offs, pairs, support, b1, agg1);
    // layer 2 (relu fused into GEMM2's input load)
    k_gemm_k64<true><<<row_grid, 256, 0, stream>>>(agg1, W2, support);
    k_gather<<<row_grid, 256, 0, stream>>>(offs, pairs, support, b2, out);
}

// Round 4
// 264.116 us; speedup vs baseline: 1.7686x; 1.0463x over previous
//
#include <hip/hip_runtime.h>

// GCN forward on MI355X (gfx950), fp32.
// R4: GEMMs restructured to 8 rows/wave (8 indep FMA chains per LDS read,
// 8x fewer LDS issues + 8x less W re-staging). ReLU moved into gather-1's
// store so GEMM2 keeps pure scalar x loads.

#define N_NODES 50000
#define N_EDGES 800000
#define IN_DIM  128
#define HID_DIM 64
#define OUT_DIM 64

#define SCAN_B 256
#define N_SCAN_BLOCKS ((N_NODES + SCAN_B - 1) / SCAN_B)   // 196

// ---------------- CSR build ----------------
__global__ __launch_bounds__(256) void k_zero(int* __restrict__ p, int n) {
    int i = blockIdx.x * 256 + threadIdx.x;
    if (i < n) p[i] = 0;
}

__global__ __launch_bounds__(256) void k_hist(const int* __restrict__ erow,
                                              int* __restrict__ counts) {
    int e = blockIdx.x * 256 + threadIdx.x;
    if (e < N_EDGES) atomicAdd(&counts[erow[e]], 1);
}

// pass 1: per-block exclusive scan of counts; block total -> partials
__global__ __launch_bounds__(SCAN_B) void k_scan1(
    const int* __restrict__ counts, int* __restrict__ offs,
    int* __restrict__ partials)
{
    __shared__ int sm[SCAN_B];
    int t = threadIdx.x;
    int i = blockIdx.x * SCAN_B + t;
    int v = (i < N_NODES) ? counts[i] : 0;
    sm[t] = v;
    __syncthreads();
    #pragma unroll
    for (int off = 1; off < SCAN_B; off <<= 1) {
        int add = (t >= off) ? sm[t - off] : 0;
        __syncthreads();
        sm[t] += add;
        __syncthreads();
    }
    if (i < N_NODES) offs[i] = sm[t] - v;            // local exclusive
    if (t == SCAN_B - 1) partials[blockIdx.x] = sm[t];
}

// pass 2: exclusive scan of the 196 block totals (single tiny block)
__global__ __launch_bounds__(SCAN_B) void k_scan2(int* __restrict__ partials)
{
    __shared__ int sm[SCAN_B];
    int t = threadIdx.x;
    int v = (t < N_SCAN_BLOCKS) ? partials[t] : 0;
    sm[t] = v;
    __syncthreads();
    #pragma unroll
    for (int off = 1; off < SCAN_B; off <<= 1) {
        int add = (t >= off) ? sm[t - off] : 0;
        __syncthreads();
        sm[t] += add;
        __syncthreads();
    }
    if (t < N_SCAN_BLOCKS) partials[t] = sm[t] - v;  // exclusive
}

// pass 3: add block base; emit final offs + cursor copy
__global__ __launch_bounds__(SCAN_B) void k_scan3(
    int* __restrict__ offs, const int* __restrict__ partials,
    int* __restrict__ cursor)
{
    int t = threadIdx.x;
    int i = blockIdx.x * SCAN_B + t;
    int base = partials[blockIdx.x];
    if (i < N_NODES) {
        int o = offs[i] + base;
        offs[i] = o;
        cursor[i] = o;
    }
    if (i == 0) offs[N_NODES] = N_EDGES;
}

// Scatter edges into row-sorted (col, val_bits) pairs.
__global__ __launch_bounds__(256) void k_reorder(
    const int* __restrict__ erow, const int* __restrict__ ecol,
    const float* __restrict__ eval_, int* __restrict__ cursor,
    uint2* __restrict__ pairs)
{
    int e = blockIdx.x * 256 + threadIdx.x;
    if (e >= N_EDGES) return;
    int r = erow[e];
    int pos = atomicAdd(&cursor[r], 1);
    pairs[pos] = make_uint2((unsigned)ecol[e], __float_as_uint(eval_[e]));
}

// ---------------- gather SpMM: out[r] = bias + sum val*dense[col] ----
// One wave per row, lane = feature dim. APPLY_RELU fuses layer-1's relu
// into the store (agg1 is only consumed by GEMM2, so this is equivalent).
template <bool APPLY_RELU>
__global__ __launch_bounds__(256) void k_gather(
    const int* __restrict__ offs, const uint2* __restrict__ pairs,
    const float* __restrict__ dense, const float* __restrict__ bias,
    float* __restrict__ out)
{
    int t = threadIdx.x;
    int r = __builtin_amdgcn_readfirstlane(blockIdx.x * 4 + (t >> 6));
    int d = t & 63;
    int e0 = offs[r], e1 = offs[r + 1];
    float acc = bias[d];
    for (int e = e0; e < e1; ++e) {
        uint2 p = pairs[e];
        acc = fmaf(__uint_as_float(p.y), dense[(size_t)p.x * 64u + d], acc);
    }
    if (APPLY_RELU) acc = fmaxf(acc, 0.f);
    out[(size_t)r * 64 + d] = acc;
}

// ---------------- GEMM: [N,K] @ [K,64] -> [N,64], 8 rows/wave --------
// Block = 256 = 4 waves; each wave computes 8 consecutive rows, lane=col.
// One LDS read of W[k][col] feeds 8 independent FMA chains; x loads are
// scalar (wave-uniform row base via readfirstlane, imm offsets).
template <int K>
__global__ __launch_bounds__(256) void k_gemm(
    const float* __restrict__ X, const float* __restrict__ W,
    float* __restrict__ out)
{
    __shared__ float Wl[K * 64];
    int t = threadIdx.x;
    #pragma unroll
    for (int i = 0; i < (K * 64) / 256; ++i)
        Wl[t + i * 256] = W[t + i * 256];
    __syncthreads();

    int col = t & 63;
    int r0 = __builtin_amdgcn_readfirstlane(blockIdx.x * 32 + (t >> 6) * 8);
    const float* xr = X + (size_t)r0 * K;

    if (r0 + 8 <= N_NODES) {
        float acc[8] = {0.f, 0.f, 0.f, 0.f, 0.f, 0.f, 0.f, 0.f};
        #pragma unroll 4
        for (int k = 0; k < K; ++k) {
            float w = Wl[k * 64 + col];
            #pragma unroll
            for (int rr = 0; rr < 8; ++rr)
                acc[rr] = fmaf(xr[(size_t)rr * K + k], w, acc[rr]);
        }
        #pragma unroll
        for (int rr = 0; rr < 8; ++rr)
            out[(size_t)(r0 + rr) * 64 + col] = acc[rr];
    } else {
        for (int rr = 0; rr < 8 && r0 + rr < N_NODES; ++rr) {
            float a = 0.f;
            for (int k = 0; k < K; ++k)
                a = fmaf(xr[(size_t)rr * K + k], Wl[k * 64 + col], a);
            out[(size_t)(r0 + rr) * 64 + col] = a;
        }
    }
}

extern "C" void kernel_launch(void* const* d_in, const int* in_sizes, int n_in,
                              void* d_out, int out_size, void* d_ws, size_t ws_size,
                              hipStream_t stream)
{
    const float* x     = (const float*)d_in[0];
    const int*   erow  = (const int*)d_in[1];
    const int*   ecol  = (const int*)d_in[2];
    const float* eval_ = (const float*)d_in[3];
    const float* W1    = (const float*)d_in[4];
    const float* b1    = (const float*)d_in[5];
    const float* W2    = (const float*)d_in[6];
    const float* b2    = (const float*)d_in[7];
    float* out = (float*)d_out;

    // ws layout (~32.6 MB):
    uint2* pairs    = (uint2*)d_ws;                                  // 6.4 MB
    float* support  = (float*)(pairs + N_EDGES);                     // 12.8 MB
    float* agg1     = support + (size_t)N_NODES * HID_DIM;           // 12.8 MB
    int*   counts   = (int*)(agg1 + (size_t)N_NODES * HID_DIM);      // 0.2 MB
    int*   offs     = counts + N_NODES;                              // 0.2 MB
    int*   cursor   = offs + (N_NODES + 1);                          // 0.2 MB
    int*   partials = cursor + N_NODES;                              // 784 B

    const int zero_grid = (N_NODES + 255) / 256;     // 196
    const int edge_grid = (N_EDGES + 255) / 256;     // 3125
    const int row_grid  = N_NODES / 4;               // 12500 (gather), exact
    const int gemm_grid = (N_NODES + 31) / 32;       // 1563

    // CSR build (shared by both layers)
    k_zero<<<zero_grid, 256, 0, stream>>>(counts, N_NODES);
    k_hist<<<edge_grid, 256, 0, stream>>>(erow, counts);
    k_scan1<<<N_SCAN_BLOCKS, SCAN_B, 0, stream>>>(counts, offs, partials);
    k_scan2<<<1, SCAN_B, 0, stream>>>(partials);
    k_scan3<<<N_SCAN_BLOCKS, SCAN_B, 0, stream>>>(offs, partials, cursor);
    k_reorder<<<edge_grid, 256, 0, stream>>>(erow, ecol, eval_, cursor, pairs);

    // layer 1 (relu fused into gather-1's store)
    k_gemm<IN_DIM><<<gemm_grid, 256, 0, stream>>>(x, W1, support);
    k_gather<true><<<row_grid, 256, 0, stream>>>(offs, pairs, support, b1, agg1);
    // layer 2
    k_gemm<HID_DIM><<<gemm_grid, 256, 0, stream>>>(agg1, W2, support);
    k_gather<false><<<row_grid, 256, 0, stream>>>(offs, pairs, support, b2, out);
}

// Round 5
// 204.191 us; speedup vs baseline: 2.2876x; 1.2935x over previous
//
#include <hip/hip_runtime.h>

// GCN forward on MI355X (gfx950).
// R5: (1) bf16 MFMA GEMMs (16x16x32) with XOR-swizzled LDS tiles —
//     the R4 scalar-load GEMM was s_load latency-bound (VALUBusy 9%).
//     (2) bucketed two-pass CSR reorder — R4's random 8B scatter wrote
//     52MB HBM for a 6.4MB buffer (full-line dirtying across XCDs).

#define N_NODES 50000
#define N_EDGES 800000
#define IN_DIM  128
#define HID_DIM 64
#define OUT_DIM 64

#define SCAN_B 256
#define N_SCAN_BLOCKS ((N_NODES + SCAN_B - 1) / SCAN_B)   // 196

#define NB  196          // row buckets (row >> 8)
#define EPB 4096         // edges per bucket-pass block
#define NBLK_E ((N_EDGES + EPB - 1) / EPB)                // 196

typedef __attribute__((ext_vector_type(8))) short bf16x8;
typedef __attribute__((ext_vector_type(4))) float f32x4;

__device__ inline unsigned short f2bf(float x) {   // RNE fp32 -> bf16
    unsigned u = __float_as_uint(x);
    return (unsigned short)((u + 0x7FFFu + ((u >> 16) & 1u)) >> 16);
}

// ---------------- utility ----------------
__global__ __launch_bounds__(256) void k_zero(int* __restrict__ p, int n) {
    int i = blockIdx.x * 256 + threadIdx.x;
    if (i < n) p[i] = 0;
}

// W[K][64] fp32 -> Wt[64][K] bf16
template <int K>
__global__ __launch_bounds__(256) void k_convW(
    const float* __restrict__ W, unsigned short* __restrict__ Wt)
{
    int e = blockIdx.x * 256 + threadIdx.x;   // grid covers K*64 exactly
    int c = e / K, k = e % K;
    Wt[c * K + k] = f2bf(W[k * 64 + c]);
}

// ---------------- CSR build: counts + bucket counts ----------------
__global__ __launch_bounds__(256) void k_bhist(
    const int* __restrict__ erow, int* __restrict__ counts,
    int* __restrict__ bcnt)
{
    __shared__ int lc[NB];
    int t = threadIdx.x;
    for (int i = t; i < NB; i += 256) lc[i] = 0;
    __syncthreads();
    int base = blockIdx.x * EPB;
    #pragma unroll 4
    for (int i = 0; i < 16; ++i) {
        int e = base + i * 256 + t;
        if (e < N_EDGES) {
            int r = erow[e];
            atomicAdd(&counts[r], 1);       // node-level (global, L2-hot)
            atomicAdd(&lc[r >> 8], 1);      // bucket-level (LDS)
        }
    }
    __syncthreads();
    for (int i = t; i < NB; i += 256)
        if (lc[i]) atomicAdd(&bcnt[i], lc[i]);
}

// hierarchical node scan (unchanged from R4, minus cursor)
__global__ __launch_bounds__(SCAN_B) void k_scan1(
    const int* __restrict__ counts, int* __restrict__ offs,
    int* __restrict__ partials)
{
    __shared__ int sm[SCAN_B];
    int t = threadIdx.x;
    int i = blockIdx.x * SCAN_B + t;
    int v = (i < N_NODES) ? counts[i] : 0;
    sm[t] = v;
    __syncthreads();
    #pragma unroll
    for (int off = 1; off < SCAN_B; off <<= 1) {
        int add = (t >= off) ? sm[t - off] : 0;
        __syncthreads();
        sm[t] += add;
        __syncthreads();
    }
    if (i < N_NODES) offs[i] = sm[t] - v;
    if (t == SCAN_B - 1) partials[blockIdx.x] = sm[t];
}

__global__ __launch_bounds__(SCAN_B) void k_scan2(int* __restrict__ partials)
{
    __shared__ int sm[SCAN_B];
    int t = threadIdx.x;
    int v = (t < N_SCAN_BLOCKS) ? partials[t] : 0;
    sm[t] = v;
    __syncthreads();
    #pragma unroll
    for (int off = 1; off < SCAN_B; off <<= 1) {
        int add = (t >= off) ? sm[t - off] : 0;
        __syncthreads();
        sm[t] += add;
        __syncthreads();
    }
    if (t < N_SCAN_BLOCKS) partials[t] = sm[t] - v;
}

__global__ __launch_bounds__(SCAN_B) void k_scan3(
    int* __restrict__ offs, const int* __restrict__ partials)
{
    int t = threadIdx.x;
    int i = blockIdx.x * SCAN_B + t;
    int base = partials[blockIdx.x];
    if (i < N_NODES) offs[i] += base;
    if (i == 0) offs[N_NODES] = N_EDGES;
}

// scan of 196 bucket counts (single tiny block)
__global__ __launch_bounds__(256) void k_bscan(
    const int* __restrict__ bcnt, int* __restrict__ boffs,
    int* __restrict__ bcur)
{
    __shared__ int sm[256];
    int t = threadIdx.x;
    int v = (t < NB) ? bcnt[t] : 0;
    sm[t] = v;
    __syncthreads();
    #pragma unroll
    for (int off = 1; off < 256; off <<= 1) {
        int add = (t >= off) ? sm[t - off] : 0;
        __syncthreads();
        sm[t] += add;
        __syncthreads();
    }
    if (t < NB) { boffs[t] = sm[t] - v; bcur[t] = sm[t] - v; }
    if (t == 0) boffs[NB] = N_EDGES;
}

// pass A: scatter edges into bucket-contiguous regions.
// bucketed word0 = col (16b) | rowlow (8b) << 16; word1 = val bits.
__global__ __launch_bounds__(256) void k_bscatter(
    const int* __restrict__ erow, const int* __restrict__ ecol,
    const float* __restrict__ eval_, int* __restrict__ bcur,
    uint2* __restrict__ bucketed)
{
    __shared__ int lc[NB];
    __shared__ int lbase[NB];
    int t = threadIdx.x;
    for (int i = t; i < NB; i += 256) lc[i] = 0;
    __syncthreads();
    int base = blockIdx.x * EPB;
    int bkt[16], rnk[16];
    #pragma unroll 4
    for (int i = 0; i < 16; ++i) {
        int e = base + i * 256 + t;
        bkt[i] = -1;
        if (e < N_EDGES) {
            bkt[i] = erow[e] >> 8;
            rnk[i] = atomicAdd(&lc[bkt[i]], 1);
        }
    }
    __syncthreads();
    for (int i = t; i < NB; i += 256)
        lbase[i] = lc[i] ? atomicAdd(&bcur[i], lc[i]) : 0;
    __syncthreads();
    #pragma unroll 4
    for (int i = 0; i < 16; ++i) {
        int e = base + i * 256 + t;
        if (bkt[i] >= 0) {
            unsigned r = (unsigned)erow[e];
            unsigned w0 = (unsigned)ecol[e] | ((r & 255u) << 16);
            bucketed[lbase[bkt[i]] + rnk[i]] =
                make_uint2(w0, __float_as_uint(eval_[e]));
        }
    }
}

// pass B: one block per bucket; LDS row cursors -> exact CSR position.
// pairs writes land in a ~32KB contiguous window (L2/line friendly).
__global__ __launch_bounds__(256) void k_bfinal(
    const int* __restrict__ boffs, const int* __restrict__ offs,
    const uint2* __restrict__ bucketed, uint2* __restrict__ pairs)
{
    __shared__ int rcur[256];
    int t = threadIdx.x;
    int b = blockIdx.x;
    int gr = (b << 8) + t;
    rcur[t] = (gr < N_NODES) ? offs[gr] : 0;
    __syncthreads();
    int e1 = boffs[b + 1];
    for (int e = boffs[b] + t; e < e1; e += 256) {
        uint2 p = bucketed[e];
        int pos = atomicAdd(&rcur[(p.x >> 16) & 255], 1);
        pairs[pos] = make_uint2(p.x & 0xFFFFu, p.y);
    }
}

// ---------------- gather SpMM (unchanged) ----------------
template <bool APPLY_RELU>
__global__ __launch_bounds__(256) void k_gather(
    const int* __restrict__ offs, const uint2* __restrict__ pairs,
    const float* __restrict__ dense, const float* __restrict__ bias,
    float* __restrict__ out)
{
    int t = threadIdx.x;
    int r = __builtin_amdgcn_readfirstlane(blockIdx.x * 4 + (t >> 6));
    int d = t & 63;
    int e0 = offs[r], e1 = offs[r + 1];
    float acc = bias[d];
    for (int e = e0; e < e1; ++e) {
        uint2 p = pairs[e];
        acc = fmaf(__uint_as_float(p.y), dense[(size_t)p.x * 64u + d], acc);
    }
    if (APPLY_RELU) acc = fmaxf(acc, 0.f);
    out[(size_t)r * 64 + d] = acc;
}

// ---------------- MFMA GEMM: [N,K] fp32 @ Wt[64][K] bf16 -> [N,64] --
// Block = 256 (4 waves), 32 rows per block. Wave w: rows 16*(w&1),
// cols 32*(w>>1). X tile converted fp32->bf16 into LDS; both LDS tiles
// XOR-swizzled (byte ^= (row&7)<<4) to break the 256B-stride bank clash.
// Frags: A[row=l&15][k=(l>>4)*8+j], B[col=l&15][same k], C col=l&15,
// row=(l>>4)*4+reg (m89-verified layout).
template <int K>
__global__ __launch_bounds__(256) void k_gemm_mfma(
    const float* __restrict__ X, const unsigned short* __restrict__ Wt,
    float* __restrict__ out)
{
    __shared__ unsigned short Al[32 * K];
    __shared__ unsigned short Bl[64 * K];
    int t = threadIdx.x;
    int m0 = blockIdx.x * 32;

    // stage B (Wt is linear bf16 [64][K]) with swizzle, 16B chunks
    #pragma unroll
    for (int i = 0; i < K / 32; ++i) {
        int u4 = i * 256 + t;                 // uint4 index
        int col = (u4 * 8) / K, k = (u4 * 8) % K;
        uint4 w = ((const uint4*)Wt)[u4];
        int byte = (col * K + k) * 2;
        byte ^= ((col & 7) << 4);
        *(uint4*)((char*)Bl + byte) = w;
    }
    // stage A: 8 floats/thread/iter -> one 16B bf16 write
    #pragma unroll
    for (int i = 0; i < K / 64; ++i) {
        int f8 = i * 256 + t;                 // 8-float group
        int row = (f8 * 8) / K, k = (f8 * 8) % K;
        int grow = m0 + row;
        float4 xa = make_float4(0.f, 0.f, 0.f, 0.f), xb = xa;
        if (grow < N_NODES) {
            const float4* src = (const float4*)(X + (size_t)grow * K + k);
            xa = src[0];
            xb = src[1];
        }
        uint4 v;
        v.x = (unsigned)f2bf(xa.x) | ((unsigned)f2bf(xa.y) << 16);
        v.y = (unsigned)f2bf(xa.z) | ((unsigned)f2bf(xa.w) << 16);
        v.z = (unsigned)f2bf(xb.x) | ((unsigned)f2bf(xb.y) << 16);
        v.w = (unsigned)f2bf(xb.z) | ((unsigned)f2bf(xb.w) << 16);
        int byte = (row * K + k) * 2;
        byte ^= ((row & 7) << 4);
        *(uint4*)((char*)Al + byte) = v;
    }
    __syncthreads();

    int w = t >> 6, l = t & 63;
    int lr0 = (w & 1) * 16;                   // LDS-local row base
    int c0  = (w >> 1) * 32;                  // col base (2 tiles: c0,c0+16)
    int lrow = lr0 + (l & 15);
    int kb = (l >> 4) * 8;
    int col0 = c0 + (l & 15), col1 = col0 + 16;
    f32x4 acc0 = {0.f, 0.f, 0.f, 0.f}, acc1 = {0.f, 0.f, 0.f, 0.f};
    #pragma unroll
    for (int kc = 0; kc < K / 32; ++kc) {
        int ka = kc * 32 + kb;
        int ab = (lrow * K + ka) * 2;  ab ^= ((lrow & 7) << 4);
        int bb0 = (col0 * K + ka) * 2; bb0 ^= ((col0 & 7) << 4);
        int bb1 = (col1 * K + ka) * 2; bb1 ^= ((col1 & 7) << 4);
        bf16x8 a  = *(const bf16x8*)((const char*)Al + ab);
        bf16x8 b0 = *(const bf16x8*)((const char*)Bl + bb0);
        bf16x8 b1 = *(const bf16x8*)((const char*)Bl + bb1);
        acc0 = __builtin_amdgcn_mfma_f32_16x16x32_bf16(a, b0, acc0, 0, 0, 0);
        acc1 = __builtin_amdgcn_mfma_f32_16x16x32_bf16(a, b1, acc1, 0, 0, 0);
    }
    int grow0 = m0 + lr0 + (l >> 4) * 4;
    #pragma unroll
    for (int j = 0; j < 4; ++j) {
        int gr = grow0 + j;
        if (gr < N_NODES) {
            out[(size_t)gr * 64 + col0] = acc0[j];
            out[(size_t)gr * 64 + col1] = acc1[j];
        }
    }
}

extern "C" void kernel_launch(void* const* d_in, const int* in_sizes, int n_in,
                              void* d_out, int out_size, void* d_ws, size_t ws_size,
                              hipStream_t stream)
{
    const float* x     = (const float*)d_in[0];
    const int*   erow  = (const int*)d_in[1];
    const int*   ecol  = (const int*)d_in[2];
    const float* eval_ = (const float*)d_in[3];
    const float* W1    = (const float*)d_in[4];
    const float* b1    = (const float*)d_in[5];
    const float* W2    = (const float*)d_in[6];
    const float* b2    = (const float*)d_in[7];
    float* out = (float*)d_out;

    // ws layout (bytes): pairs 6,400,000 | support 12,800,000 |
    // agg1 12,800,000 (bucketed aliases this — dead before gather1 writes)
    // | Wt1 16KB | Wt2 8KB | int arrays.
    uint2* pairs    = (uint2*)d_ws;
    float* support  = (float*)(pairs + N_EDGES);
    float* agg1     = support + (size_t)N_NODES * HID_DIM;
    uint2* bucketed = (uint2*)agg1;                         // alias
    unsigned short* Wt1 = (unsigned short*)(agg1 + (size_t)N_NODES * HID_DIM);
    unsigned short* Wt2 = Wt1 + IN_DIM * HID_DIM;
    int* counts   = (int*)(Wt2 + HID_DIM * OUT_DIM);
    int* bcnt     = counts + N_NODES;           // contiguous with counts
    int* offs     = bcnt + NB;
    int* boffs    = offs + (N_NODES + 1);
    int* bcur     = boffs + (NB + 1);
    int* partials = bcur + NB;

    const int zero_grid = (N_NODES + NB + 255) / 256;
    const int row_grid  = N_NODES / 4;               // 12500 (gather)
    const int gemm_grid = (N_NODES + 31) / 32;       // 1563

    // weight conversion (independent)
    k_convW<IN_DIM><<<(IN_DIM * HID_DIM) / 256, 256, 0, stream>>>(W1, Wt1);
    k_convW<HID_DIM><<<(HID_DIM * OUT_DIM) / 256, 256, 0, stream>>>(W2, Wt2);

    // CSR build
    k_zero<<<zero_grid, 256, 0, stream>>>(counts, N_NODES + NB);
    k_bhist<<<NBLK_E, 256, 0, stream>>>(erow, counts, bcnt);
    k_scan1<<<N_SCAN_BLOCKS, SCAN_B, 0, stream>>>(counts, offs, partials);
    k_scan2<<<1, SCAN_B, 0, stream>>>(partials);
    k_scan3<<<N_SCAN_BLOCKS, SCAN_B, 0, stream>>>(offs, partials);
    k_bscan<<<1, 256, 0, stream>>>(bcnt, boffs, bcur);
    k_bscatter<<<NBLK_E, 256, 0, stream>>>(erow, ecol, eval_, bcur, bucketed);
    k_bfinal<<<NB, 256, 0, stream>>>(boffs, offs, bucketed, pairs);

    // layer 1 (relu fused into gather-1's store; gather1 overwrites the
    // bucketed alias, which is dead after k_bfinal)
    k_gemm_mfma<IN_DIM><<<gemm_grid, 256, 0, stream>>>(x, Wt1, support);
    k_gather<true><<<row_grid, 256, 0, stream>>>(offs, pairs, support, b1, agg1);
    // layer 2
    k_gemm_mfma<HID_DIM><<<gemm_grid, 256, 0, stream>>>(agg1, Wt2, support);
    k_gather<false><<<row_grid, 256, 0, stream>>>(offs, pairs, support, b2, out);
}

// Round 6
// 149.492 us; speedup vs baseline: 3.1246x; 1.3659x over previous
//
#include <hip/hip_runtime.h>

// GCN forward on MI355X (gfx950).
// R6: gather was latency+L2-fill bound (52us each, FETCH 81.5MB = dense
// duplicated into 8 XCD L2s, ~1 load in flight). Fix: (1) bf16 dense
// (halves random-read bytes + L2 footprint; GEMM2 eats bf16 A directly),
// (2) 4-way edge unroll with 4 accumulators for MLP.

#define N_NODES 50000
#define N_EDGES 800000
#define IN_DIM  128
#define HID_DIM 64
#define OUT_DIM 64

#define SCAN_B 256
#define N_SCAN_BLOCKS ((N_NODES + SCAN_B - 1) / SCAN_B)   // 196

#define NB  196          // row buckets (row >> 8)
#define EPB 4096         // edges per bucket-pass block
#define NBLK_E ((N_EDGES + EPB - 1) / EPB)                // 196

typedef __attribute__((ext_vector_type(8))) short bf16x8;
typedef __attribute__((ext_vector_type(4))) float f32x4;

__device__ inline unsigned short f2bf(float x) {   // RNE fp32 -> bf16
    unsigned u = __float_as_uint(x);
    return (unsigned short)((u + 0x7FFFu + ((u >> 16) & 1u)) >> 16);
}
__device__ inline float bf2f(unsigned v) {
    return __uint_as_float(v << 16);
}

// ---------------- utility ----------------
__global__ __launch_bounds__(256) void k_zero(int* __restrict__ p, int n) {
    int i = blockIdx.x * 256 + threadIdx.x;
    if (i < n) p[i] = 0;
}

// W[K][64] fp32 -> Wt[64][K] bf16
template <int K>
__global__ __launch_bounds__(256) void k_convW(
    const float* __restrict__ W, unsigned short* __restrict__ Wt)
{
    int e = blockIdx.x * 256 + threadIdx.x;   // grid covers K*64 exactly
    int c = e / K, k = e % K;
    Wt[c * K + k] = f2bf(W[k * 64 + c]);
}

// ---------------- CSR build: counts + bucket counts ----------------
__global__ __launch_bounds__(256) void k_bhist(
    const int* __restrict__ erow, int* __restrict__ counts,
    int* __restrict__ bcnt)
{
    __shared__ int lc[NB];
    int t = threadIdx.x;
    for (int i = t; i < NB; i += 256) lc[i] = 0;
    __syncthreads();
    int base = blockIdx.x * EPB;
    #pragma unroll 4
    for (int i = 0; i < 16; ++i) {
        int e = base + i * 256 + t;
        if (e < N_EDGES) {
            int r = erow[e];
            atomicAdd(&counts[r], 1);       // node-level (global, L2-hot)
            atomicAdd(&lc[r >> 8], 1);      // bucket-level (LDS)
        }
    }
    __syncthreads();
    for (int i = t; i < NB; i += 256)
        if (lc[i]) atomicAdd(&bcnt[i], lc[i]);
}

// hierarchical node scan
__global__ __launch_bounds__(SCAN_B) void k_scan1(
    const int* __restrict__ counts, int* __restrict__ offs,
    int* __restrict__ partials)
{
    __shared__ int sm[SCAN_B];
    int t = threadIdx.x;
    int i = blockIdx.x * SCAN_B + t;
    int v = (i < N_NODES) ? counts[i] : 0;
    sm[t] = v;
    __syncthreads();
    #pragma unroll
    for (int off = 1; off < SCAN_B; off <<= 1) {
        int add = (t >= off) ? sm[t - off] : 0;
        __syncthreads();
        sm[t] += add;
        __syncthreads();
    }
    if (i < N_NODES) offs[i] = sm[t] - v;
    if (t == SCAN_B - 1) partials[blockIdx.x] = sm[t];
}

__global__ __launch_bounds__(SCAN_B) void k_scan2(int* __restrict__ partials)
{
    __shared__ int sm[SCAN_B];
    int t = threadIdx.x;
    int v = (t < N_SCAN_BLOCKS) ? partials[t] : 0;
    sm[t] = v;
    __syncthreads();
    #pragma unroll
    for (int off = 1; off < SCAN_B; off <<= 1) {
        int add = (t >= off) ? sm[t - off] : 0;
        __syncthreads();
        sm[t] += add;
        __syncthreads();
    }
    if (t < N_SCAN_BLOCKS) partials[t] = sm[t] - v;
}

__global__ __launch_bounds__(SCAN_B) void k_scan3(
    int* __restrict__ offs, const int* __restrict__ partials)
{
    int t = threadIdx.x;
    int i = blockIdx.x * SCAN_B + t;
    int base = partials[blockIdx.x];
    if (i < N_NODES) offs[i] += base;
    if (i == 0) offs[N_NODES] = N_EDGES;
}

// scan of 196 bucket counts (single tiny block)
__global__ __launch_bounds__(256) void k_bscan(
    const int* __restrict__ bcnt, int* __restrict__ boffs,
    int* __restrict__ bcur)
{
    __shared__ int sm[256];
    int t = threadIdx.x;
    int v = (t < NB) ? bcnt[t] : 0;
    sm[t] = v;
    __syncthreads();
    #pragma unroll
    for (int off = 1; off < 256; off <<= 1) {
        int add = (t >= off) ? sm[t - off] : 0;
        __syncthreads();
        sm[t] += add;
        __syncthreads();
    }
    if (t < NB) { boffs[t] = sm[t] - v; bcur[t] = sm[t] - v; }
    if (t == 0) boffs[NB] = N_EDGES;
}

// pass A: scatter edges into bucket-contiguous regions.
__global__ __launch_bounds__(256) void k_bscatter(
    const int* __restrict__ erow, const int* __restrict__ ecol,
    const float* __restrict__ eval_, int* __restrict__ bcur,
    uint2* __restrict__ bucketed)
{
    __shared__ int lc[NB];
    __shared__ int lbase[NB];
    int t = threadIdx.x;
    for (int i = t; i < NB; i += 256) lc[i] = 0;
    __syncthreads();
    int base = blockIdx.x * EPB;
    int bkt[16], rnk[16];
    #pragma unroll 4
    for (int i = 0; i < 16; ++i) {
        int e = base + i * 256 + t;
        bkt[i] = -1;
        if (e < N_EDGES) {
            bkt[i] = erow[e] >> 8;
            rnk[i] = atomicAdd(&lc[bkt[i]], 1);
        }
    }
    __syncthreads();
    for (int i = t; i < NB; i += 256)
        lbase[i] = lc[i] ? atomicAdd(&bcur[i], lc[i]) : 0;
    __syncthreads();
    #pragma unroll 4
    for (int i = 0; i < 16; ++i) {
        int e = base + i * 256 + t;
        if (bkt[i] >= 0) {
            unsigned r = (unsigned)erow[e];
            unsigned w0 = (unsigned)ecol[e] | ((r & 255u) << 16);
            bucketed[lbase[bkt[i]] + rnk[i]] =
                make_uint2(w0, __float_as_uint(eval_[e]));
        }
    }
}

// pass B: one block per bucket; LDS row cursors -> exact CSR position.
__global__ __launch_bounds__(256) void k_bfinal(
    const int* __restrict__ boffs, const int* __restrict__ offs,
    const uint2* __restrict__ bucketed, uint2* __restrict__ pairs)
{
    __shared__ int rcur[256];
    int t = threadIdx.x;
    int b = blockIdx.x;
    int gr = (b << 8) + t;
    rcur[t] = (gr < N_NODES) ? offs[gr] : 0;
    __syncthreads();
    int e1 = boffs[b + 1];
    for (int e = boffs[b] + t; e < e1; e += 256) {
        uint2 p = bucketed[e];
        int pos = atomicAdd(&rcur[(p.x >> 16) & 255], 1);
        pairs[pos] = make_uint2(p.x & 0xFFFFu, p.y);
    }
}

// ---------------- gather SpMM: bf16 dense, 4-way edge unroll --------
// One wave per row, lane = feature dim. 4 independent accumulators give
// 4 random 128B reads in flight (the R5 loop had ~1 -> latency-bound).
template <bool APPLY_RELU, bool OUT_BF16>
__global__ __launch_bounds__(256) void k_gather(
    const int* __restrict__ offs, const uint2* __restrict__ pairs,
    const unsigned short* __restrict__ dense, const float* __restrict__ bias,
    void* __restrict__ outp)
{
    int t = threadIdx.x;
    int r = __builtin_amdgcn_readfirstlane(blockIdx.x * 4 + (t >> 6));
    int d = t & 63;
    int e0 = offs[r], e1 = offs[r + 1];
    float a0 = bias[d], a1 = 0.f, a2 = 0.f, a3 = 0.f;
    int e = e0;
    for (; e + 4 <= e1; e += 4) {
        uint2 p0 = pairs[e], p1 = pairs[e + 1];
        uint2 p2 = pairs[e + 2], p3 = pairs[e + 3];
        unsigned v0 = dense[(size_t)p0.x * 64u + d];
        unsigned v1 = dense[(size_t)p1.x * 64u + d];
        unsigned v2 = dense[(size_t)p2.x * 64u + d];
        unsigned v3 = dense[(size_t)p3.x * 64u + d];
        a0 = fmaf(__uint_as_float(p0.y), bf2f(v0), a0);
        a1 = fmaf(__uint_as_float(p1.y), bf2f(v1), a1);
        a2 = fmaf(__uint_as_float(p2.y), bf2f(v2), a2);
        a3 = fmaf(__uint_as_float(p3.y), bf2f(v3), a3);
    }
    for (; e < e1; ++e) {
        uint2 p = pairs[e];
        unsigned v = dense[(size_t)p.x * 64u + d];
        a0 = fmaf(__uint_as_float(p.y), bf2f(v), a0);
    }
    float acc = (a0 + a1) + (a2 + a3);
    if (APPLY_RELU) acc = fmaxf(acc, 0.f);
    if (OUT_BF16)
        ((unsigned short*)outp)[(size_t)r * 64 + d] = f2bf(acc);
    else
        ((float*)outp)[(size_t)r * 64 + d] = acc;
}

// ---------------- MFMA GEMM: A[N,K] @ Wt[64][K] bf16 -> bf16 [N,64] --
// Block = 256 (4 waves), 32 rows/block. A input either fp32 (layer 1, X)
// or bf16 (layer 2, agg1). Both LDS tiles XOR-swizzled
// (byte ^= (row&7)<<4). Output stored bf16 (gather consumes bf16).
template <int K, bool IN_BF16>
__global__ __launch_bounds__(256) void k_gemm_mfma(
    const void* __restrict__ Xv, const unsigned short* __restrict__ Wt,
    unsigned short* __restrict__ out)
{
    __shared__ unsigned short Al[32 * K];
    __shared__ unsigned short Bl[64 * K];
    int t = threadIdx.x;
    int m0 = blockIdx.x * 32;

    // stage B (Wt linear bf16 [64][K]) with swizzle, 16B chunks
    #pragma unroll
    for (int i = 0; i < K / 32; ++i) {
        int u4 = i * 256 + t;                 // uint4 index
        int col = (u4 * 8) / K, k = (u4 * 8) % K;
        uint4 w = ((const uint4*)Wt)[u4];
        int byte = (col * K + k) * 2;
        byte ^= ((col & 7) << 4);
        *(uint4*)((char*)Bl + byte) = w;
    }
    // stage A
    if (IN_BF16) {
        // K=64: 32 rows x 64 bf16 = 256 x ushort8, exactly one per thread
        const unsigned short* X = (const unsigned short*)Xv;
        int row = t / (K / 8), k = (t % (K / 8)) * 8;
        int grow = m0 + row;
        uint4 v = make_uint4(0, 0, 0, 0);
        if (grow < N_NODES)
            v = *(const uint4*)(X + (size_t)grow * K + k);
        int byte = (row * K + k) * 2;
        byte ^= ((row & 7) << 4);
        *(uint4*)((char*)Al + byte) = v;
    } else {
        const float* X = (const float*)Xv;
        #pragma unroll
        for (int i = 0; i < K / 64; ++i) {
            int f8 = i * 256 + t;             // 8-float group
            int row = (f8 * 8) / K, k = (f8 * 8) % K;
            int grow = m0 + row;
            float4 xa = make_float4(0.f, 0.f, 0.f, 0.f), xb = xa;
            if (grow < N_NODES) {
                const float4* src = (const float4*)(X + (size_t)grow * K + k);
                xa = src[0];
                xb = src[1];
            }
            uint4 v;
            v.x = (unsigned)f2bf(xa.x) | ((unsigned)f2bf(xa.y) << 16);
            v.y = (unsigned)f2bf(xa.z) | ((unsigned)f2bf(xa.w) << 16);
            v.z = (unsigned)f2bf(xb.x) | ((unsigned)f2bf(xb.y) << 16);
            v.w = (unsigned)f2bf(xb.z) | ((unsigned)f2bf(xb.w) << 16);
            int byte = (row * K + k) * 2;
            byte ^= ((row & 7) << 4);
            *(uint4*)((char*)Al + byte) = v;
        }
    }
    __syncthreads();

    int w = t >> 6, l = t & 63;
    int lr0 = (w & 1) * 16;                   // LDS-local row base
    int c0  = (w >> 1) * 32;                  // col base (2 tiles)
    int lrow = lr0 + (l & 15);
    int kb = (l >> 4) * 8;
    int col0 = c0 + (l & 15), col1 = col0 + 16;
    f32x4 acc0 = {0.f, 0.f, 0.f, 0.f}, acc1 = {0.f, 0.f, 0.f, 0.f};
    #pragma unroll
    for (int kc = 0; kc < K / 32; ++kc) {
        int ka = kc * 32 + kb;
        int ab = (lrow * K + ka) * 2;  ab ^= ((lrow & 7) << 4);
        int bb0 = (col0 * K + ka) * 2; bb0 ^= ((col0 & 7) << 4);
        int bb1 = (col1 * K + ka) * 2; bb1 ^= ((col1 & 7) << 4);
        bf16x8 a  = *(const bf16x8*)((const char*)Al + ab);
        bf16x8 b0 = *(const bf16x8*)((const char*)Bl + bb0);
        bf16x8 b1 = *(const bf16x8*)((const char*)Bl + bb1);
        acc0 = __builtin_amdgcn_mfma_f32_16x16x32_bf16(a, b0, acc0, 0, 0, 0);
        acc1 = __builtin_amdgcn_mfma_f32_16x16x32_bf16(a, b1, acc1, 0, 0, 0);
    }
    int grow0 = m0 + lr0 + (l >> 4) * 4;
    #pragma unroll
    for (int j = 0; j < 4; ++j) {
        int gr = grow0 + j;
        if (gr < N_NODES) {
            out[(size_t)gr * 64 + col0] = f2bf(acc0[j]);
            out[(size_t)gr * 64 + col1] = f2bf(acc1[j]);
        }
    }
}

extern "C" void kernel_launch(void* const* d_in, const int* in_sizes, int n_in,
                              void* d_out, int out_size, void* d_ws, size_t ws_size,
                              hipStream_t stream)
{
    const float* x     = (const float*)d_in[0];
    const int*   erow  = (const int*)d_in[1];
    const int*   ecol  = (const int*)d_in[2];
    const float* eval_ = (const float*)d_in[3];
    const float* W1    = (const float*)d_in[4];
    const float* b1    = (const float*)d_in[5];
    const float* W2    = (const float*)d_in[6];
    const float* b2    = (const float*)d_in[7];
    float* out = (float*)d_out;

    // ws layout: pairs 6.4MB | support bf16 6.4MB | agg1 bf16 6.4MB
    // (bucketed aliases agg1 — dead before gather1 writes) | Wt1 | Wt2 | ints
    uint2* pairs = (uint2*)d_ws;
    unsigned short* support = (unsigned short*)(pairs + N_EDGES);
    unsigned short* agg1 = support + (size_t)N_NODES * 64;
    uint2* bucketed = (uint2*)agg1;                         // alias, 6.4MB
    unsigned short* Wt1 = agg1 + (size_t)N_NODES * 64;
    unsigned short* Wt2 = Wt1 + IN_DIM * HID_DIM;
    int* counts   = (int*)(Wt2 + HID_DIM * OUT_DIM);
    int* bcnt     = counts + N_NODES;           // contiguous with counts
    int* offs     = bcnt + NB;
    int* boffs    = offs + (N_NODES + 1);
    int* bcur     = boffs + (NB + 1);
    int* partials = bcur + NB;

    const int zero_grid = (N_NODES + NB + 255) / 256;
    const int row_grid  = N_NODES / 4;               // 12500 (gather)
    const int gemm_grid = (N_NODES + 31) / 32;       // 1563

    // weight conversion (independent)
    k_convW<IN_DIM><<<(IN_DIM * HID_DIM) / 256, 256, 0, stream>>>(W1, Wt1);
    k_convW<HID_DIM><<<(HID_DIM * OUT_DIM) / 256, 256, 0, stream>>>(W2, Wt2);

    // CSR build
    k_zero<<<zero_grid, 256, 0, stream>>>(counts, N_NODES + NB);
    k_bhist<<<NBLK_E, 256, 0, stream>>>(erow, counts, bcnt);
    k_scan1<<<N_SCAN_BLOCKS, SCAN_B, 0, stream>>>(counts, offs, partials);
    k_scan2<<<1, SCAN_B, 0, stream>>>(partials);
    k_scan3<<<N_SCAN_BLOCKS, SCAN_B, 0, stream>>>(offs, partials);
    k_bscan<<<1, 256, 0, stream>>>(bcnt, boffs, bcur);
    k_bscatter<<<NBLK_E, 256, 0, stream>>>(erow, ecol, eval_, bcur, bucketed);
    k_bfinal<<<NB, 256, 0, stream>>>(boffs, offs, bucketed, pairs);

    // layer 1 (relu fused into gather-1's bf16 store; gather1 overwrites
    // the bucketed alias, which is dead after k_bfinal)
    k_gemm_mfma<IN_DIM, false><<<gemm_grid, 256, 0, stream>>>(x, Wt1, support);
    k_gather<true, true><<<row_grid, 256, 0, stream>>>(offs, pairs, support, b1, agg1);
    // layer 2
    k_gemm_mfma<HID_DIM, true><<<gemm_grid, 256, 0, stream>>>(agg1, Wt2, support);
    k_gather<false, false><<<row_grid, 256, 0, stream>>>(offs, pairs, support, b2, out);
}

// Round 7
// 109.296 us; speedup vs baseline: 4.2738x; 1.3678x over previous
//
#include <hip/hip_runtime.h>

// GCN forward on MI355X (gfx950).
// R7: CSR build collapsed — k_bfinal now does per-bucket row-count +
// in-block scan + offs write + scatter (bucket base == CSR base since
// buckets partition rows in order), deleting the node histogram and all
// three node-scan kernels. Gather: 8-way edge unroll (8 loads in flight).

#define N_NODES 50000
#define N_EDGES 800000
#define IN_DIM  128
#define HID_DIM 64
#define OUT_DIM 64

#define NB  196          // row buckets (row >> 8)
#define EPB 4096         // edges per bucket-pass block
#define NBLK_E ((N_EDGES + EPB - 1) / EPB)                // 196
#define BF_CAP 6144      // LDS edge cache per bucket (48KB); E[bucket]=4096, sigma=64

typedef __attribute__((ext_vector_type(8))) short bf16x8;
typedef __attribute__((ext_vector_type(4))) float f32x4;

__device__ inline unsigned short f2bf(float x) {   // RNE fp32 -> bf16
    unsigned u = __float_as_uint(x);
    return (unsigned short)((u + 0x7FFFu + ((u >> 16) & 1u)) >> 16);
}
__device__ inline float bf2f(unsigned v) {
    return __uint_as_float(v << 16);
}

// ---------------- utility ----------------
__global__ __launch_bounds__(256) void k_zero(int* __restrict__ p, int n) {
    int i = blockIdx.x * 256 + threadIdx.x;
    if (i < n) p[i] = 0;
}

// both weights, one launch: W[K][64] fp32 -> Wt[64][K] bf16
__global__ __launch_bounds__(256) void k_convW(
    const float* __restrict__ W1, unsigned short* __restrict__ Wt1,
    const float* __restrict__ W2, unsigned short* __restrict__ Wt2)
{
    int e = blockIdx.x * 256 + threadIdx.x;   // grid covers 12288 exactly
    if (e < IN_DIM * HID_DIM) {
        int c = e / IN_DIM, k = e % IN_DIM;
        Wt1[c * IN_DIM + k] = f2bf(W1[k * HID_DIM + c]);
    } else {
        int e2 = e - IN_DIM * HID_DIM;
        int c = e2 / HID_DIM, k = e2 % HID_DIM;
        Wt2[c * HID_DIM + k] = f2bf(W2[k * OUT_DIM + c]);
    }
}

// ---------------- bucket histogram (LDS-only, 196 global atomics/blk) --
__global__ __launch_bounds__(256) void k_bhist(
    const int* __restrict__ erow, int* __restrict__ bcnt)
{
    __shared__ int lc[NB];
    int t = threadIdx.x;
    for (int i = t; i < NB; i += 256) lc[i] = 0;
    __syncthreads();
    int base = blockIdx.x * EPB;
    #pragma unroll 4
    for (int i = 0; i < 16; ++i) {
        int e = base + i * 256 + t;
        if (e < N_EDGES) atomicAdd(&lc[erow[e] >> 8], 1);
    }
    __syncthreads();
    for (int i = t; i < NB; i += 256)
        if (lc[i]) atomicAdd(&bcnt[i], lc[i]);
}

// scan of 196 bucket counts (single tiny block); also seeds sentinels
__global__ __launch_bounds__(256) void k_bscan(
    const int* __restrict__ bcnt, int* __restrict__ boffs,
    int* __restrict__ bcur, int* __restrict__ offs)
{
    __shared__ int sm[256];
    int t = threadIdx.x;
    int v = (t < NB) ? bcnt[t] : 0;
    sm[t] = v;
    __syncthreads();
    #pragma unroll
    for (int off = 1; off < 256; off <<= 1) {
        int add = (t >= off) ? sm[t - off] : 0;
        __syncthreads();
        sm[t] += add;
        __syncthreads();
    }
    if (t < NB) { boffs[t] = sm[t] - v; bcur[t] = sm[t] - v; }
    if (t == 0) { boffs[NB] = N_EDGES; offs[N_NODES] = N_EDGES; }
}

// pass A: scatter edges into bucket-contiguous regions.
// word0 = col (16b) | rowlow (8b) << 16; word1 = val bits.
__global__ __launch_bounds__(256) void k_bscatter(
    const int* __restrict__ erow, const int* __restrict__ ecol,
    const float* __restrict__ eval_, int* __restrict__ bcur,
    uint2* __restrict__ bucketed)
{
    __shared__ int lc[NB];
    __shared__ int lbase[NB];
    int t = threadIdx.x;
    for (int i = t; i < NB; i += 256) lc[i] = 0;
    __syncthreads();
    int base = blockIdx.x * EPB;
    int bkt[16], rnk[16];
    #pragma unroll 4
    for (int i = 0; i < 16; ++i) {
        int e = base + i * 256 + t;
        bkt[i] = -1;
        if (e < N_EDGES) {
            bkt[i] = erow[e] >> 8;
            rnk[i] = atomicAdd(&lc[bkt[i]], 1);
        }
    }
    __syncthreads();
    for (int i = t; i < NB; i += 256)
        lbase[i] = lc[i] ? atomicAdd(&bcur[i], lc[i]) : 0;
    __syncthreads();
    #pragma unroll 4
    for (int i = 0; i < 16; ++i) {
        int e = base + i * 256 + t;
        if (bkt[i] >= 0) {
            unsigned r = (unsigned)erow[e];
            unsigned w0 = (unsigned)ecol[e] | ((r & 255u) << 16);
            bucketed[lbase[bkt[i]] + rnk[i]] =
                make_uint2(w0, __float_as_uint(eval_[e]));
        }
    }
}

// pass B: one block per bucket. Edges cached in LDS; per-row count ->
// in-block scan -> offs (bucket base IS the CSR base) -> scatter.
__global__ __launch_bounds__(256) void k_bfinal(
    const int* __restrict__ boffs, int* __restrict__ offs,
    const uint2* __restrict__ bucketed, uint2* __restrict__ pairs)
{
    __shared__ uint2 ebuf[BF_CAP];
    __shared__ int rcnt[256];
    __shared__ int rsc[256];
    int t = threadIdx.x;
    int b = blockIdx.x;
    int e0 = boffs[b], e1 = boffs[b + 1];
    int ne = e1 - e0;
    rcnt[t] = 0;
    __syncthreads();
    bool cached = (ne <= BF_CAP);   // E[ne]=4096, sigma~64; fallback kept
    for (int i = t; i < ne; i += 256) {
        uint2 p = bucketed[e0 + i];
        if (cached) ebuf[i] = p;
        atomicAdd(&rcnt[(p.x >> 16) & 255], 1);
    }
    __syncthreads();
    int v = rcnt[t];
    rsc[t] = v;
    __syncthreads();
    #pragma unroll
    for (int off = 1; off < 256; off <<= 1) {
        int add = (t >= off) ? rsc[t - off] : 0;
        __syncthreads();
        rsc[t] += add;
        __syncthreads();
    }
    int base = e0 + rsc[t] - v;          // global CSR offset of row gr
    int gr = (b << 8) + t;
    if (gr < N_NODES) offs[gr] = base;
    rcnt[t] = base;                      // becomes the row cursor
    __syncthreads();
    for (int i = t; i < ne; i += 256) {
        uint2 p = cached ? ebuf[i] : bucketed[e0 + i];
        int pos = atomicAdd(&rcnt[(p.x >> 16) & 255], 1);
        pairs[pos] = make_uint2(p.x & 0xFFFFu, p.y);
    }
}

// ---------------- gather SpMM: bf16 dense, 8-way edge unroll --------
// One wave per row, lane = feature dim; 8 independent accumulators keep
// 8 random 128B dense reads in flight. Pair loads are scalar (r, e are
// wave-uniform).
template <bool APPLY_RELU, bool OUT_BF16>
__global__ __launch_bounds__(256) void k_gather(
    const int* __restrict__ offs, const uint2* __restrict__ pairs,
    const unsigned short* __restrict__ dense, const float* __restrict__ bias,
    void* __restrict__ outp)
{
    int t = threadIdx.x;
    int r = __builtin_amdgcn_readfirstlane(blockIdx.x * 4 + (t >> 6));
    int d = t & 63;
    int e0 = offs[r], e1 = offs[r + 1];
    float a[8];
    a[0] = bias[d];
    #pragma unroll
    for (int i = 1; i < 8; ++i) a[i] = 0.f;
    int e = e0;
    for (; e + 8 <= e1; e += 8) {
        uint2 p[8];
        #pragma unroll
        for (int i = 0; i < 8; ++i) p[i] = pairs[e + i];
        unsigned v[8];
        #pragma unroll
        for (int i = 0; i < 8; ++i) v[i] = dense[(size_t)p[i].x * 64u + d];
        #pragma unroll
        for (int i = 0; i < 8; ++i)
            a[i] = fmaf(__uint_as_float(p[i].y), bf2f(v[i]), a[i]);
    }
    if (e + 4 <= e1) {
        uint2 p[4];
        #pragma unroll
        for (int i = 0; i < 4; ++i) p[i] = pairs[e + i];
        unsigned v[4];
        #pragma unroll
        for (int i = 0; i < 4; ++i) v[i] = dense[(size_t)p[i].x * 64u + d];
        #pragma unroll
        for (int i = 0; i < 4; ++i)
            a[i] = fmaf(__uint_as_float(p[i].y), bf2f(v[i]), a[i]);
        e += 4;
    }
    for (; e < e1; ++e) {
        uint2 p = pairs[e];
        a[0] = fmaf(__uint_as_float(p.y),
                    bf2f(dense[(size_t)p.x * 64u + d]), a[0]);
    }
    float acc = ((a[0] + a[1]) + (a[2] + a[3])) +
                ((a[4] + a[5]) + (a[6] + a[7]));
    if (APPLY_RELU) acc = fmaxf(acc, 0.f);
    if (OUT_BF16)
        ((unsigned short*)outp)[(size_t)r * 64 + d] = f2bf(acc);
    else
        ((float*)outp)[(size_t)r * 64 + d] = acc;
}

// ---------------- MFMA GEMM: A[N,K] @ Wt[64][K] bf16 -> bf16 [N,64] --
// Block = 256 (4 waves), 32 rows/block. A input fp32 (layer 1) or bf16
// (layer 2). Both LDS tiles XOR-swizzled (byte ^= (row&7)<<4).
template <int K, bool IN_BF16>
__global__ __launch_bounds__(256) void k_gemm_mfma(
    const void* __restrict__ Xv, const unsigned short* __restrict__ Wt,
    unsigned short* __restrict__ out)
{
    __shared__ unsigned short Al[32 * K];
    __shared__ unsigned short Bl[64 * K];
    int t = threadIdx.x;
    int m0 = blockIdx.x * 32;

    #pragma unroll
    for (int i = 0; i < K / 32; ++i) {
        int u4 = i * 256 + t;                 // uint4 index
        int col = (u4 * 8) / K, k = (u4 * 8) % K;
        uint4 w = ((const uint4*)Wt)[u4];
        int byte = (col * K + k) * 2;
        byte ^= ((col & 7) << 4);
        *(uint4*)((char*)Bl + byte) = w;
    }
    if (IN_BF16) {
        const unsigned short* X = (const unsigned short*)Xv;
        int row = t / (K / 8), k = (t % (K / 8)) * 8;
        int grow = m0 + row;
        uint4 v = make_uint4(0, 0, 0, 0);
        if (grow < N_NODES)
            v = *(const uint4*)(X + (size_t)grow * K + k);
        int byte = (row * K + k) * 2;
        byte ^= ((row & 7) << 4);
        *(uint4*)((char*)Al + byte) = v;
    } else {
        const float* X = (const float*)Xv;
        #pragma unroll
        for (int i = 0; i < K / 64; ++i) {
            int f8 = i * 256 + t;             // 8-float group
            int row = (f8 * 8) / K, k = (f8 * 8) % K;
            int grow = m0 + row;
            float4 xa = make_float4(0.f, 0.f, 0.f, 0.f), xb = xa;
            if (grow < N_NODES) {
                const float4* src = (const float4*)(X + (size_t)grow * K + k);
                xa = src[0];
                xb = src[1];
            }
            uint4 v;
            v.x = (unsigned)f2bf(xa.x) | ((unsigned)f2bf(xa.y) << 16);
            v.y = (unsigned)f2bf(xa.z) | ((unsigned)f2bf(xa.w) << 16);
            v.z = (unsigned)f2bf(xb.x) | ((unsigned)f2bf(xb.y) << 16);
            v.w = (unsigned)f2bf(xb.z) | ((unsigned)f2bf(xb.w) << 16);
            int byte = (row * K + k) * 2;
            byte ^= ((row & 7) << 4);
            *(uint4*)((char*)Al + byte) = v;
        }
    }
    __syncthreads();

    int w = t >> 6, l = t & 63;
    int lr0 = (w & 1) * 16;
    int c0  = (w >> 1) * 32;
    int lrow = lr0 + (l & 15);
    int kb = (l >> 4) * 8;
    int col0 = c0 + (l & 15), col1 = col0 + 16;
    f32x4 acc0 = {0.f, 0.f, 0.f, 0.f}, acc1 = {0.f, 0.f, 0.f, 0.f};
    #pragma unroll
    for (int kc = 0; kc < K / 32; ++kc) {
        int ka = kc * 32 + kb;
        int ab = (lrow * K + ka) * 2;  ab ^= ((lrow & 7) << 4);
        int bb0 = (col0 * K + ka) * 2; bb0 ^= ((col0 & 7) << 4);
        int bb1 = (col1 * K + ka) * 2; bb1 ^= ((col1 & 7) << 4);
        bf16x8 a  = *(const bf16x8*)((const char*)Al + ab);
        bf16x8 b0 = *(const bf16x8*)((const char*)Bl + bb0);
        bf16x8 b1 = *(const bf16x8*)((const char*)Bl + bb1);
        acc0 = __builtin_amdgcn_mfma_f32_16x16x32_bf16(a, b0, acc0, 0, 0, 0);
        acc1 = __builtin_amdgcn_mfma_f32_16x16x32_bf16(a, b1, acc1, 0, 0, 0);
    }
    int grow0 = m0 + lr0 + (l >> 4) * 4;
    #pragma unroll
    for (int j = 0; j < 4; ++j) {
        int gr = grow0 + j;
        if (gr < N_NODES) {
            out[(size_t)gr * 64 + col0] = f2bf(acc0[j]);
            out[(size_t)gr * 64 + col1] = f2bf(acc1[j]);
        }
    }
}

extern "C" void kernel_launch(void* const* d_in, const int* in_sizes, int n_in,
                              void* d_out, int out_size, void* d_ws, size_t ws_size,
                              hipStream_t stream)
{
    const float* x     = (const float*)d_in[0];
    const int*   erow  = (const int*)d_in[1];
    const int*   ecol  = (const int*)d_in[2];
    const float* eval_ = (const float*)d_in[3];
    const float* W1    = (const float*)d_in[4];
    const float* b1    = (const float*)d_in[5];
    const float* W2    = (const float*)d_in[6];
    const float* b2    = (const float*)d_in[7];
    float* out = (float*)d_out;

    // ws: pairs 6.4MB | support bf16 6.4MB | agg1 bf16 6.4MB (bucketed
    // aliases agg1, dead before gather1 writes) | Wt1 | Wt2 | ints
    uint2* pairs = (uint2*)d_ws;
    unsigned short* support = (unsigned short*)(pairs + N_EDGES);
    unsigned short* agg1 = support + (size_t)N_NODES * 64;
    uint2* bucketed = (uint2*)agg1;                         // alias, 6.4MB
    unsigned short* Wt1 = agg1 + (size_t)N_NODES * 64;
    unsigned short* Wt2 = Wt1 + IN_DIM * HID_DIM;
    int* bcnt  = (int*)(Wt2 + HID_DIM * OUT_DIM);
    int* boffs = bcnt + NB;
    int* bcur  = boffs + (NB + 1);
    int* offs  = bcur + NB;                    // N_NODES + 1 ints

    const int row_grid  = N_NODES / 4;               // 12500 (gather)
    const int gemm_grid = (N_NODES + 31) / 32;       // 1563

    // weight conversion + CSR build
    k_convW<<<(IN_DIM * HID_DIM + HID_DIM * OUT_DIM) / 256, 256, 0, stream>>>(
        W1, Wt1, W2, Wt2);
    k_zero<<<1, 256, 0, stream>>>(bcnt, NB);
    k_bhist<<<NBLK_E, 256, 0, stream>>>(erow, bcnt);
    k_bscan<<<1, 256, 0, stream>>>(bcnt, boffs, bcur, offs);
    k_bscatter<<<NBLK_E, 256, 0, stream>>>(erow, ecol, eval_, bcur, bucketed);
    k_bfinal<<<NB, 256, 0, stream>>>(boffs, offs, bucketed, pairs);

    // layer 1 (relu fused into gather-1's bf16 store)
    k_gemm_mfma<IN_DIM, false><<<gemm_grid, 256, 0, stream>>>(x, Wt1, support);
    k_gather<true, true><<<row_grid, 256, 0, stream>>>(offs, pairs, support, b1, agg1);
    // layer 2
    k_gemm_mfma<HID_DIM, true><<<gemm_grid, 256, 0, stream>>>(agg1, Wt2, support);
    k_gather<false, false><<<row_grid, 256, 0, stream>>>(offs, pairs, support, b2, out);
}

// Round 8
// 95.067 us; speedup vs baseline: 4.9134x; 1.1497x over previous
//
#include <hip/hip_runtime.h>

// GCN forward on MI355X (gfx950).
// R8: fixed-capacity bucket padding (BCAP=5120 >> 4096+16sigma) kills the
// bucket histogram + scan kernels; per-row CSR extents stored as int2
// (start,end) into the padded pairs array. 10 dispatches -> 7.

#define N_NODES 50000
#define N_EDGES 800000
#define IN_DIM  128
#define HID_DIM 64
#define OUT_DIM 64

#define NB   196         // row buckets (row >> 8); bucket b owns rows [b*256, ...)
#define EPB  4096        // edges per bscatter block
#define NBLK_E ((N_EDGES + EPB - 1) / EPB)   // 196
#define BCAP 5120        // padded region per bucket; E[cnt]=4096, sigma~64

typedef __attribute__((ext_vector_type(8))) short bf16x8;
typedef __attribute__((ext_vector_type(4))) float f32x4;

__device__ inline unsigned short f2bf(float x) {   // RNE fp32 -> bf16
    unsigned u = __float_as_uint(x);
    return (unsigned short)((u + 0x7FFFu + ((u >> 16) & 1u)) >> 16);
}
__device__ inline float bf2f(unsigned v) {
    return __uint_as_float(v << 16);
}

// ---------------- prep: weight transpose+bf16 convert, bcur zero ------
// grid = 49 blocks: 0-31 -> Wt1, 32-47 -> Wt2, 48 -> zero bcur.
__global__ __launch_bounds__(256) void k_prep(
    const float* __restrict__ W1, unsigned short* __restrict__ Wt1,
    const float* __restrict__ W2, unsigned short* __restrict__ Wt2,
    int* __restrict__ bcur)
{
    int b = blockIdx.x, t = threadIdx.x;
    if (b < 32) {                       // IN_DIM*HID_DIM = 8192 = 32*256
        int e = b * 256 + t;
        int c = e / IN_DIM, k = e % IN_DIM;
        Wt1[c * IN_DIM + k] = f2bf(W1[k * HID_DIM + c]);
    } else if (b < 48) {                // HID_DIM*OUT_DIM = 4096 = 16*256
        int e2 = (b - 32) * 256 + t;
        int c = e2 / HID_DIM, k = e2 % HID_DIM;
        Wt2[c * HID_DIM + k] = f2bf(W2[k * OUT_DIM + c]);
    } else {
        if (t < NB) bcur[t] = 0;
    }
}

// ---------------- pass A: scatter edges into padded bucket regions ----
// word0 = col (16b) | rowlow (8b) << 16; word1 = val bits.
// One atomicAdd per (bucket, block) reserves a contiguous run.
__global__ __launch_bounds__(256) void k_bscatter(
    const int* __restrict__ erow, const int* __restrict__ ecol,
    const float* __restrict__ eval_, int* __restrict__ bcur,
    uint2* __restrict__ bucketed)
{
    __shared__ int lc[NB];
    __shared__ int lbase[NB];
    int t = threadIdx.x;
    for (int i = t; i < NB; i += 256) lc[i] = 0;
    __syncthreads();
    int base = blockIdx.x * EPB;
    int bkt[16], rnk[16];
    #pragma unroll 4
    for (int i = 0; i < 16; ++i) {
        int e = base + i * 256 + t;
        bkt[i] = -1;
        if (e < N_EDGES) {
            bkt[i] = erow[e] >> 8;
            rnk[i] = atomicAdd(&lc[bkt[i]], 1);
        }
    }
    __syncthreads();
    for (int i = t; i < NB; i += 256)
        lbase[i] = lc[i] ? atomicAdd(&bcur[i], lc[i]) : 0;
    __syncthreads();
    #pragma unroll 4
    for (int i = 0; i < 16; ++i) {
        int e = base + i * 256 + t;
        if (bkt[i] >= 0) {
            unsigned r = (unsigned)erow[e];
            unsigned w0 = (unsigned)ecol[e] | ((r & 255u) << 16);
            bucketed[(size_t)bkt[i] * BCAP + lbase[bkt[i]] + rnk[i]] =
                make_uint2(w0, __float_as_uint(eval_[e]));
        }
    }
}

// ---------------- pass B: one block per bucket ------------------------
// LDS-cache the bucket's edges; per-row count -> in-block scan ->
// offs2[row] = (start,end) absolute into padded pairs -> row-sorted scatter.
__global__ __launch_bounds__(256) void k_bfinal(
    const int* __restrict__ bcur, const uint2* __restrict__ bucketed,
    uint2* __restrict__ pairs, int2* __restrict__ offs2)
{
    __shared__ uint2 ebuf[BCAP];        // 40 KB
    __shared__ int rcnt[256];
    __shared__ int rsc[256];
    int t = threadIdx.x, b = blockIdx.x;
    int ne = bcur[b];                   // actual edges in this bucket
    int base0 = b * BCAP;
    rcnt[t] = 0;
    __syncthreads();
    for (int i = t; i < ne; i += 256) {
        uint2 p = bucketed[(size_t)base0 + i];
        ebuf[i] = p;
        atomicAdd(&rcnt[(p.x >> 16) & 255], 1);
    }
    __syncthreads();
    int v = rcnt[t];
    rsc[t] = v;
    __syncthreads();
    #pragma unroll
    for (int off = 1; off < 256; off <<= 1) {
        int add = (t >= off) ? rsc[t - off] : 0;
        __syncthreads();
        rsc[t] += add;
        __syncthreads();
    }
    int start = base0 + rsc[t] - v;
    int gr = (b << 8) + t;
    if (gr < N_NODES) offs2[gr] = make_int2(start, start + v);
    rcnt[t] = start;                    // becomes row cursor
    __syncthreads();
    for (int i = t; i < ne; i += 256) {
        uint2 p = ebuf[i];
        int pos = atomicAdd(&rcnt[(p.x >> 16) & 255], 1);
        pairs[pos] = make_uint2(p.x & 0xFFFFu, p.y);
    }
}

// ---------------- gather SpMM: bf16 dense, 8-way edge unroll ----------
// One wave per row, lane = feature dim; 8 independent accumulators keep
// 8 random 128B dense reads in flight. r/e0/e1 wave-uniform (scalar).
template <bool APPLY_RELU, bool OUT_BF16>
__global__ __launch_bounds__(256) void k_gather(
    const int2* __restrict__ offs2, const uint2* __restrict__ pairs,
    const unsigned short* __restrict__ dense, const float* __restrict__ bias,
    void* __restrict__ outp)
{
    int t = threadIdx.x;
    int r = __builtin_amdgcn_readfirstlane(blockIdx.x * 4 + (t >> 6));
    int d = t & 63;
    int2 oe = offs2[r];
    int e0 = oe.x, e1 = oe.y;
    float a[8];
    a[0] = bias[d];
    #pragma unroll
    for (int i = 1; i < 8; ++i) a[i] = 0.f;
    int e = e0;
    for (; e + 8 <= e1; e += 8) {
        uint2 p[8];
        #pragma unroll
        for (int i = 0; i < 8; ++i) p[i] = pairs[e + i];
        unsigned v[8];
        #pragma unroll
        for (int i = 0; i < 8; ++i) v[i] = dense[(size_t)p[i].x * 64u + d];
        #pragma unroll
        for (int i = 0; i < 8; ++i)
            a[i] = fmaf(__uint_as_float(p[i].y), bf2f(v[i]), a[i]);
    }
    if (e + 4 <= e1) {
        uint2 p[4];
        #pragma unroll
        for (int i = 0; i < 4; ++i) p[i] = pairs[e + i];
        unsigned v[4];
        #pragma unroll
        for (int i = 0; i < 4; ++i) v[i] = dense[(size_t)p[i].x * 64u + d];
        #pragma unroll
        for (int i = 0; i < 4; ++i)
            a[i] = fmaf(__uint_as_float(p[i].y), bf2f(v[i]), a[i]);
        e += 4;
    }
    for (; e < e1; ++e) {
        uint2 p = pairs[e];
        a[0] = fmaf(__uint_as_float(p.y),
                    bf2f(dense[(size_t)p.x * 64u + d]), a[0]);
    }
    float acc = ((a[0] + a[1]) + (a[2] + a[3])) +
                ((a[4] + a[5]) + (a[6] + a[7]));
    if (APPLY_RELU) acc = fmaxf(acc, 0.f);
    if (OUT_BF16)
        ((unsigned short*)outp)[(size_t)r * 64 + d] = f2bf(acc);
    else
        ((float*)outp)[(size_t)r * 64 + d] = acc;
}

// ---------------- MFMA GEMM: A[N,K] @ Wt[64][K] bf16 -> bf16 [N,64] ---
// Block = 256 (4 waves), 32 rows/block. A input fp32 (layer 1) or bf16
// (layer 2). Both LDS tiles XOR-swizzled (byte ^= (row&7)<<4).
template <int K, bool IN_BF16>
__global__ __launch_bounds__(256) void k_gemm_mfma(
    const void* __restrict__ Xv, const unsigned short* __restrict__ Wt,
    unsigned short* __restrict__ out)
{
    __shared__ unsigned short Al[32 * K];
    __shared__ unsigned short Bl[64 * K];
    int t = threadIdx.x;
    int m0 = blockIdx.x * 32;

    #pragma unroll
    for (int i = 0; i < K / 32; ++i) {
        int u4 = i * 256 + t;                 // uint4 index
        int col = (u4 * 8) / K, k = (u4 * 8) % K;
        uint4 w = ((const uint4*)Wt)[u4];
        int byte = (col * K + k) * 2;
        byte ^= ((col & 7) << 4);
        *(uint4*)((char*)Bl + byte) = w;
    }
    if (IN_BF16) {
        const unsigned short* X = (const unsigned short*)Xv;
        int row = t / (K / 8), k = (t % (K / 8)) * 8;
        int grow = m0 + row;
        uint4 v = make_uint4(0, 0, 0, 0);
        if (grow < N_NODES)
            v = *(const uint4*)(X + (size_t)grow * K + k);
        int byte = (row * K + k) * 2;
        byte ^= ((row & 7) << 4);
        *(uint4*)((char*)Al + byte) = v;
    } else {
        const float* X = (const float*)Xv;
        #pragma unroll
        for (int i = 0; i < K / 64; ++i) {
            int f8 = i * 256 + t;             // 8-float group
            int row = (f8 * 8) / K, k = (f8 * 8) % K;
            int grow = m0 + row;
            float4 xa = make_float4(0.f, 0.f, 0.f, 0.f), xb = xa;
            if (grow < N_NODES) {
                const float4* src = (const float4*)(X + (size_t)grow * K + k);
                xa = src[0];
                xb = src[1];
            }
            uint4 v;
            v.x = (unsigned)f2bf(xa.x) | ((unsigned)f2bf(xa.y) << 16);
            v.y = (unsigned)f2bf(xa.z) | ((unsigned)f2bf(xa.w) << 16);
            v.z = (unsigned)f2bf(xb.x) | ((unsigned)f2bf(xb.y) << 16);
            v.w = (unsigned)f2bf(xb.z) | ((unsigned)f2bf(xb.w) << 16);
            int byte = (row * K + k) * 2;
            byte ^= ((row & 7) << 4);
            *(uint4*)((char*)Al + byte) = v;
        }
    }
    __syncthreads();

    int w = t >> 6, l = t & 63;
    int lr0 = (w & 1) * 16;
    int c0  = (w >> 1) * 32;
    int lrow = lr0 + (l & 15);
    int kb = (l >> 4) * 8;
    int col0 = c0 + (l & 15), col1 = col0 + 16;
    f32x4 acc0 = {0.f, 0.f, 0.f, 0.f}, acc1 = {0.f, 0.f, 0.f, 0.f};
    #pragma unroll
    for (int kc = 0; kc < K / 32; ++kc) {
        int ka = kc * 32 + kb;
        int ab = (lrow * K + ka) * 2;  ab ^= ((lrow & 7) << 4);
        int bb0 = (col0 * K + ka) * 2; bb0 ^= ((col0 & 7) << 4);
        int bb1 = (col1 * K + ka) * 2; bb1 ^= ((col1 & 7) << 4);
        bf16x8 a  = *(const bf16x8*)((const char*)Al + ab);
        bf16x8 b0 = *(const bf16x8*)((const char*)Bl + bb0);
        bf16x8 b1 = *(const bf16x8*)((const char*)Bl + bb1);
        acc0 = __builtin_amdgcn_mfma_f32_16x16x32_bf16(a, b0, acc0, 0, 0, 0);
        acc1 = __builtin_amdgcn_mfma_f32_16x16x32_bf16(a, b1, acc1, 0, 0, 0);
    }
    int grow0 = m0 + lr0 + (l >> 4) * 4;
    #pragma unroll
    for (int j = 0; j < 4; ++j) {
        int gr = grow0 + j;
        if (gr < N_NODES) {
            out[(size_t)gr * 64 + col0] = f2bf(acc0[j]);
            out[(size_t)gr * 64 + col1] = f2bf(acc1[j]);
        }
    }
}

extern "C" void kernel_launch(void* const* d_in, const int* in_sizes, int n_in,
                              void* d_out, int out_size, void* d_ws, size_t ws_size,
                              hipStream_t stream)
{
    const float* x     = (const float*)d_in[0];
    const int*   erow  = (const int*)d_in[1];
    const int*   ecol  = (const int*)d_in[2];
    const float* eval_ = (const float*)d_in[3];
    const float* W1    = (const float*)d_in[4];
    const float* b1    = (const float*)d_in[5];
    const float* W2    = (const float*)d_in[6];
    const float* b2    = (const float*)d_in[7];
    float* out = (float*)d_out;

    // ws (~30 MB of 256 MB): padded pairs 8.03MB | padded bucketed 8.03MB |
    // support bf16 6.4MB | agg1 bf16 6.4MB | Wt1 | Wt2 | bcur | offs2
    uint2* pairs    = (uint2*)d_ws;
    uint2* bucketed = pairs + (size_t)NB * BCAP;
    unsigned short* support = (unsigned short*)(bucketed + (size_t)NB * BCAP);
    unsigned short* agg1 = support + (size_t)N_NODES * 64;
    unsigned short* Wt1 = agg1 + (size_t)N_NODES * 64;
    unsigned short* Wt2 = Wt1 + IN_DIM * HID_DIM;
    int*  bcur  = (int*)(Wt2 + HID_DIM * OUT_DIM);
    int2* offs2 = (int2*)(bcur + NB + 2);      // 8B-aligned (even int count)

    const int row_grid  = N_NODES / 4;               // 12500 (gather)
    const int gemm_grid = (N_NODES + 31) / 32;       // 1563

    // CSR build: 3 dispatches
    k_prep<<<49, 256, 0, stream>>>(W1, Wt1, W2, Wt2, bcur);
    k_bscatter<<<NBLK_E, 256, 0, stream>>>(erow, ecol, eval_, bcur, bucketed);
    k_bfinal<<<NB, 256, 0, stream>>>(bcur, bucketed, pairs, offs2);

    // layer 1 (relu fused into gather-1's bf16 store)
    k_gemm_mfma<IN_DIM, false><<<gemm_grid, 256, 0, stream>>>(x, Wt1, support);
    k_gather<true, true><<<row_grid, 256, 0, stream>>>(offs2, pairs, support, b1, agg1);
    // layer 2
    k_gemm_mfma<HID_DIM, true><<<gemm_grid, 256, 0, stream>>>(agg1, Wt2, support);
    k_gather<false, false><<<row_grid, 256, 0, stream>>>(offs2, pairs, support, b2, out);
}